// Round 20
// baseline (348.463 us; speedup 1.0000x reference)
//
#include <hip/hip_runtime.h>
#include <math.h>
#include <float.h>

#define IN_D 256
#define OUT_D 128
#define ED_D 64
#define NEG 0.2f

typedef __attribute__((ext_vector_type(8))) short bf16x8;
typedef __attribute__((ext_vector_type(4))) float f32x4;

__device__ __forceinline__ unsigned short f2bf(float f) {
    unsigned u = __float_as_uint(f);
    unsigned r = (u + 0x7FFFu + ((u >> 16) & 1u)) >> 16;   // RNE
    return (unsigned short)r;
}
__device__ __forceinline__ float bf2f(unsigned short h) {
    return __uint_as_float((unsigned)h << 16);
}

// K0: zero cnt; build Wb (bf16 W_fc^T pre-swizzled into MFMA B-fragment layout);
// build Wt2 (W_edge^T as float2 for k_xmm); fold ex_t branch into u, c0.
__global__ __launch_bounds__(256) void k_init(
        const float* __restrict__ W_att, const float* __restrict__ b_att,
        const float* __restrict__ W_eatt, const float* __restrict__ b_eatt,
        const float* __restrict__ W_fc, const float* __restrict__ W_edge,
        float* __restrict__ u, float* __restrict__ c0,
        unsigned short* __restrict__ Wb, float2* __restrict__ Wt2,
        int* __restrict__ cnt, int N) {
    int idx = blockIdx.x * 256 + threadIdx.x;
    if (idx < N) cnt[idx] = 0;
    if (idx < IN_D * OUT_D) {                 // 32768 = 8ks * 8nt * 64lane * 8i
        int i = idx & 7;
        int lane = (idx >> 3) & 63;
        int rest = idx >> 9;
        int nt = rest & 7, ks = rest >> 3;
        int col = nt * 16 + (lane & 15);
        int k = ks * 32 + (lane >> 4) * 8 + i;
        Wb[idx] = f2bf(W_fc[col * IN_D + k]);
    }
    if (idx < ED_D * (OUT_D / 2)) {           // 4096: Wt2[k*64+l] = {We[2l][k], We[2l+1][k]}
        int k = idx >> 6, l = idx & 63;
        Wt2[idx] = make_float2(W_edge[(2 * l) * ED_D + k], W_edge[(2 * l + 1) * ED_D + k]);
    }
    if (idx < ED_D) {
        float acc = 0.f;
        for (int j = 0; j < ED_D; ++j) acc += W_att[256 + j] * W_eatt[j * ED_D + idx];
        u[idx] = acc;
    }
    if (idx == ED_D) {
        float c = 0.f;
        for (int j = 0; j < ED_D; ++j) c += W_att[256 + j] * b_eatt[j];
        c0[0] = c + b_att[0];
    }
}

// K1: dst-degree histogram + per-edge within-bucket rank (atomic return value, free).
__global__ __launch_bounds__(256) void k_hist(const int* __restrict__ dst,
                                              int* __restrict__ cnt,
                                              int* __restrict__ rank, int E) {
    int i = blockIdx.x * 256 + threadIdx.x;
    if (i < E) rank[i] = atomicAdd(&cnt[dst[i]], 1);
}

// K2: bf16-MFMA GEMM  z = nfeat @ W_fc^T + b_fc  [N,128], f32 accumulate.
// BM=64 (was 128): LDS 34 KB -> 4 blocks/CU cap, grid 782 (~3 blocks/CU resident),
// 2x wave parallelism for latency hiding. Wave w = one 16-row m-tile x 8 n-tiles.
#define LDA 272
__global__ __launch_bounds__(256) void k_node(
        const float* __restrict__ nfeat, const unsigned short* __restrict__ Wb,
        const float* __restrict__ b_fc, const float* __restrict__ W_att,
        unsigned short* __restrict__ zb, float* __restrict__ asrc,
        float* __restrict__ adst, int n) {
    __shared__ unsigned short sa[64 * LDA];   // 34 KB
    int t = threadIdx.x;
    int row_base = blockIdx.x * 64;

    int r8 = t >> 3, c8 = t & 7;
#pragma unroll
    for (int p = 0; p < 2; ++p) {
        int r = p * 32 + r8;
        int node = row_base + r; if (node >= n) node = n - 1;
        const float4* srcp = (const float4*)(nfeat + (size_t)node * IN_D);
#pragma unroll
        for (int q = 0; q < 8; ++q) {
            int c4 = q * 8 + c8;
            float4 v = srcp[c4];
            unsigned pk0 = (unsigned)f2bf(v.x) | ((unsigned)f2bf(v.y) << 16);
            unsigned pk1 = (unsigned)f2bf(v.z) | ((unsigned)f2bf(v.w) << 16);
            *(uint2*)&sa[(size_t)r * LDA + c4 * 4] = make_uint2(pk0, pk1);
        }
    }
    __syncthreads();

    int lane = t & 63, w = t >> 6;
    int lr = lane & 15, lg = lane >> 4;

    f32x4 acc[8];
#pragma unroll
    for (int nt = 0; nt < 8; ++nt) acc[nt] = (f32x4)(0.f);

    const bf16x8* wb8 = (const bf16x8*)Wb;
#pragma unroll
    for (int ks = 0; ks < 8; ++ks) {
        bf16x8 af = *(const bf16x8*)&sa[(size_t)(w * 16 + lr) * LDA + ks * 32 + lg * 8];
        bf16x8 bfr[8];
#pragma unroll
        for (int nt = 0; nt < 8; ++nt)
            bfr[nt] = wb8[(ks * 8 + nt) * 64 + lane];
#pragma unroll
        for (int nt = 0; nt < 8; ++nt)
            acc[nt] = __builtin_amdgcn_mfma_f32_16x16x32_bf16(af, bfr[nt], acc[nt], 0, 0, 0);
    }

    // epilogue: C layout col = nt*16+lr, row = lg*4 + reg (within wave's 16-row tile)
    float w1c[8], w2c[8], bfc[8];
#pragma unroll
    for (int nt = 0; nt < 8; ++nt) {
        int col = nt * 16 + lr;
        w1c[nt] = W_att[col];
        w2c[nt] = W_att[128 + col];
        bfc[nt] = b_fc[col];
    }
    float p1[4] = {0.f, 0.f, 0.f, 0.f}, p2[4] = {0.f, 0.f, 0.f, 0.f};
#pragma unroll
    for (int nt = 0; nt < 8; ++nt) {
#pragma unroll
        for (int reg = 0; reg < 4; ++reg) {
            float zv = acc[nt][reg] + bfc[nt];
            int m = row_base + w * 16 + lg * 4 + reg;
            if (m < n) zb[(size_t)m * OUT_D + nt * 16 + lr] = f2bf(zv);
            p1[reg] = fmaf(zv, w1c[nt], p1[reg]);
            p2[reg] = fmaf(zv, w2c[nt], p2[reg]);
        }
    }
#pragma unroll
    for (int reg = 0; reg < 4; ++reg) {
#pragma unroll
        for (int off = 1; off <= 8; off <<= 1) {
            p1[reg] += __shfl_xor(p1[reg], off);
            p2[reg] += __shfl_xor(p2[reg], off);
        }
    }
    if (lr == 0) {
#pragma unroll
        for (int reg = 0; reg < 4; ++reg) {
            int m = row_base + w * 16 + lg * 4 + reg;
            if (m < n) { asrc[m] = p1[reg]; adst[m] = p2[reg]; }
        }
    }
}

// K3: exclusive scan of cnt -> rowptr (single block).
__global__ __launch_bounds__(1024) void k_scan(const int* __restrict__ cnt,
                                               int* __restrict__ rowptr, int N) {
    int t = threadIdx.x;
    int per = (N + 1023) / 1024;
    int b0 = t * per, b1 = b0 + per;
    if (b0 > N) b0 = N;
    if (b1 > N) b1 = N;
    int s = 0;
    for (int i = b0; i < b1; ++i) s += cnt[i];
    int wl = t & 63, w = t >> 6;
    int v = s;
#pragma unroll
    for (int off = 1; off < 64; off <<= 1) {
        int a = __shfl_up(v, off);
        if (wl >= off) v += a;
    }
    __shared__ int wsum[16], woff[16];
    if (wl == 63) wsum[w] = v;
    __syncthreads();
    if (t == 0) { int r = 0; for (int i = 0; i < 16; ++i) { woff[i] = r; r += wsum[i]; } }
    __syncthreads();
    int run = woff[w] + v - s;
    for (int i = b0; i < b1; ++i) { rowptr[i] = run; run += cnt[i]; }
    if (t == 1023) rowptr[N] = run;
}

// K4: build CSR edge/src lists (atomic-free via rank).
__global__ __launch_bounds__(256) void k_fill(
        const int* __restrict__ dst, const int* __restrict__ src,
        const int* __restrict__ rank, const int* __restrict__ rowptr,
        int* __restrict__ eid_csr, int* __restrict__ src_csr, int E) {
    int i = blockIdx.x * 256 + threadIdx.x;
    if (i >= E) return;
    int d = dst[i];
    int pos = rowptr[d] + rank[i];
    eid_csr[pos] = i;
    src_csr[pos] = src[i];
}

// K5 (fused edge-score + softmax + gather): one wave per node, no LDS.
// Pass A: QUAD-chain tier (16 edges/iter, 4 independent load+reduce chains).
// Pass B: 16-edge tier + 8/4/2 remainder tiers. Softmax wave-local.
__global__ __launch_bounds__(256) void k_fused(
        const unsigned short* __restrict__ zb, const float* __restrict__ ex,
        const int* __restrict__ eid_csr, const int* __restrict__ src_csr,
        const int* __restrict__ rowptr,
        const float* __restrict__ asrc, const float* __restrict__ adst,
        const float* __restrict__ u, const float* __restrict__ c0,
        float* __restrict__ h, float* __restrict__ alpha_out,
        float* __restrict__ xsum, int N) {
    int lane = threadIdx.x & 63;
    int half = lane >> 5, hl = lane & 31;
    int n = blockIdx.x * 4 + (threadIdx.x >> 6);
    if (n >= N) return;
    int beg = rowptr[n], end = rowptr[n + 1];
    int deg = end - beg;
    if (deg == 0) return;   // k_xmm writes h=0
    float adn = adst[n], cc = c0[0];
    const float2* ex2 = (const float2*)ex;
    const ushort4* z4 = (const ushort4*)zb;

    if (deg <= 64) {
        int el = 0, sl = 0;
        if (lane < deg) {
            el = eid_csr[beg + lane];
            sl = src_csr[beg + lane];
        }
        // ---- pass A: logits (quarter-wave float4, QUAD independent chains) ----
        int qh = lane >> 4, ql = lane & 15;
        const float4* ex4 = (const float4*)ex;
        float4 u4q = ((const float4*)u)[ql];
        float lg = -FLT_MAX;
        for (int j = 0; j < deg; j += 16) {
            int jq[4], eq[4];
#pragma unroll
            for (int cch = 0; cch < 4; ++cch) {
                jq[cch] = j + 4 * cch + qh;
                eq[cch] = __shfl(el, (jq[cch] < deg) ? jq[cch] : (deg - 1));
            }
            float4 xv[4];
#pragma unroll
            for (int cch = 0; cch < 4; ++cch)
                xv[cch] = ex4[(size_t)eq[cch] * 16 + ql];
            float d[4];
#pragma unroll
            for (int cch = 0; cch < 4; ++cch)
                d[cch] = fmaf(xv[cch].x, u4q.x, fmaf(xv[cch].y, u4q.y,
                          fmaf(xv[cch].z, u4q.z, xv[cch].w * u4q.w)));
#pragma unroll
            for (int off = 8; off >= 1; off >>= 1) {
#pragma unroll
                for (int cch = 0; cch < 4; ++cch)
                    d[cch] += __shfl_xor(d[cch], off);
            }
            int rel = lane - j;
            int src_lane = (rel & 3) * 16;      // quarter q holds edge (base + q)'s dot
            float dl[4];
#pragma unroll
            for (int cch = 0; cch < 4; ++cch)
                dl[cch] = __shfl(d[cch], src_lane);
            if (lane < deg && rel >= 0 && rel < 16)
                lg = dl[rel >> 2];
        }
        if (lane < deg) {
            lg += asrc[sl] + adn + cc;
            lg = (lg > 0.f) ? lg : NEG * lg;
        }
        // ---- softmax ----
        float m = lg;
#pragma unroll
        for (int off = 32; off >= 1; off >>= 1) m = fmaxf(m, __shfl_xor(m, off));
        float wvv = (lane < deg) ? expf(lg - m) : 0.f;
        float sw = wvv;
#pragma unroll
        for (int off = 32; off >= 1; off >>= 1) sw += __shfl_xor(sw, off);
        float al = wvv / sw;          // 0 for invalid lanes
        if (lane < deg) alpha_out[el] = al;
        // ---- pass B: weighted accumulation (rows L2-hot from pass A) ----
        float4 accz = make_float4(0.f, 0.f, 0.f, 0.f);
        float2 accx = make_float2(0.f, 0.f);
        int j = 0;
        for (; j + 16 <= deg; j += 16) {   // 8 pairs = 16 edges, 16 loads in flight
            float a[8]; int s[8], e[8];
#pragma unroll
            for (int q = 0; q < 8; ++q) {
                int idx = j + 2 * q + half;
                a[q] = __shfl(al, idx);
                s[q] = __shfl(sl, idx);
                e[q] = __shfl(el, idx);
            }
            ushort4 zu[8]; float2 xv[8];
#pragma unroll
            for (int q = 0; q < 8; ++q) {
                zu[q] = z4[(size_t)s[q] * 32 + hl];
                xv[q] = ex2[(size_t)e[q] * 32 + hl];
            }
#pragma unroll
            for (int q = 0; q < 8; ++q) {
                accz.x = fmaf(a[q], bf2f(zu[q].x), accz.x);
                accz.y = fmaf(a[q], bf2f(zu[q].y), accz.y);
                accz.z = fmaf(a[q], bf2f(zu[q].z), accz.z);
                accz.w = fmaf(a[q], bf2f(zu[q].w), accz.w);
                accx.x = fmaf(a[q], xv[q].x, accx.x);
                accx.y = fmaf(a[q], xv[q].y, accx.y);
            }
        }
        if (j + 8 <= deg) {              // 4 pairs = 8 edges
            float a[4]; int s[4], e[4];
#pragma unroll
            for (int q = 0; q < 4; ++q) {
                int idx = j + 2 * q + half;
                a[q] = __shfl(al, idx);
                s[q] = __shfl(sl, idx);
                e[q] = __shfl(el, idx);
            }
            ushort4 zu[4]; float2 xv[4];
#pragma unroll
            for (int q = 0; q < 4; ++q) {
                zu[q] = z4[(size_t)s[q] * 32 + hl];
                xv[q] = ex2[(size_t)e[q] * 32 + hl];
            }
#pragma unroll
            for (int q = 0; q < 4; ++q) {
                accz.x = fmaf(a[q], bf2f(zu[q].x), accz.x);
                accz.y = fmaf(a[q], bf2f(zu[q].y), accz.y);
                accz.z = fmaf(a[q], bf2f(zu[q].z), accz.z);
                accz.w = fmaf(a[q], bf2f(zu[q].w), accz.w);
                accx.x = fmaf(a[q], xv[q].x, accx.x);
                accx.y = fmaf(a[q], xv[q].y, accx.y);
            }
            j += 8;
        }
        if (j + 4 <= deg) {              // 2 pairs = 4 edges
            float a[2]; int s[2], e[2];
#pragma unroll
            for (int q = 0; q < 2; ++q) {
                int idx = j + 2 * q + half;
                a[q] = __shfl(al, idx);
                s[q] = __shfl(sl, idx);
                e[q] = __shfl(el, idx);
            }
            ushort4 zu[2]; float2 xv[2];
#pragma unroll
            for (int q = 0; q < 2; ++q) {
                zu[q] = z4[(size_t)s[q] * 32 + hl];
                xv[q] = ex2[(size_t)e[q] * 32 + hl];
            }
#pragma unroll
            for (int q = 0; q < 2; ++q) {
                accz.x = fmaf(a[q], bf2f(zu[q].x), accz.x);
                accz.y = fmaf(a[q], bf2f(zu[q].y), accz.y);
                accz.z = fmaf(a[q], bf2f(zu[q].z), accz.z);
                accz.w = fmaf(a[q], bf2f(zu[q].w), accz.w);
                accx.x = fmaf(a[q], xv[q].x, accx.x);
                accx.y = fmaf(a[q], xv[q].y, accx.y);
            }
            j += 4;
        }
        for (; j < deg; j += 2) {
            int idx = j + half;           // invalid -> al=0, s=e=0 (safe)
            float a = __shfl(al, idx);
            int s = __shfl(sl, idx), e = __shfl(el, idx);
            ushort4 zu = z4[(size_t)s * 32 + hl];
            float2 xv = ex2[(size_t)e * 32 + hl];
            accz.x = fmaf(a, bf2f(zu.x), accz.x);
            accz.y = fmaf(a, bf2f(zu.y), accz.y);
            accz.z = fmaf(a, bf2f(zu.z), accz.z);
            accz.w = fmaf(a, bf2f(zu.w), accz.w);
            accx.x = fmaf(a, xv.x, accx.x);
            accx.y = fmaf(a, xv.y, accx.y);
        }
        accz.x += __shfl_xor(accz.x, 32);
        accz.y += __shfl_xor(accz.y, 32);
        accz.z += __shfl_xor(accz.z, 32);
        accz.w += __shfl_xor(accz.w, 32);
        accx.x += __shfl_xor(accx.x, 32);
        accx.y += __shfl_xor(accx.y, 32);
        if (half == 0) {
            ((float4*)h)[(size_t)n * 32 + hl] = accz;
            ((float2*)xsum)[(size_t)n * 32 + hl] = accx;
        }
    } else {
        // rare slow path (deg>64): online softmax with on-the-fly dot recompute.
        float uv = u[lane];
        float m = -FLT_MAX, ssum = 0.f;
        for (int i = beg; i < end; ++i) {
            int e = eid_csr[i];
            float xv = ex[(size_t)e * ED_D + lane];
            float p = xv * uv;
#pragma unroll
            for (int off = 32; off >= 1; off >>= 1) p += __shfl_xor(p, off);
            float lg = p + asrc[src_csr[i]] + adn + cc;
            lg = (lg > 0.f) ? lg : NEG * lg;
            float mn = fmaxf(m, lg);
            ssum = ssum * expf(m - mn) + expf(lg - mn);
            m = mn;
        }
        float rden = 1.f / ssum;
        const ushort2* z2 = (const ushort2*)zb;
        float2 accz2 = make_float2(0.f, 0.f);
        float accxs = 0.f;
        for (int i = beg; i < end; ++i) {
            int e = eid_csr[i];
            int s = src_csr[i];
            float xv = ex[(size_t)e * ED_D + lane];
            float p = xv * uv;
#pragma unroll
            for (int off = 32; off >= 1; off >>= 1) p += __shfl_xor(p, off);
            float lg = p + asrc[s] + adn + cc;
            lg = (lg > 0.f) ? lg : NEG * lg;
            float al = expf(lg - m) * rden;
            if (lane == 0) alpha_out[e] = al;
            accxs = fmaf(al, xv, accxs);
            ushort2 zz = z2[(size_t)s * ED_D + lane];
            accz2.x = fmaf(al, bf2f(zz.x), accz2.x);
            accz2.y = fmaf(al, bf2f(zz.y), accz2.y);
        }
        ((float2*)h)[(size_t)n * ED_D + lane] = accz2;
        xsum[(size_t)n * ED_D + lane] = accxs;
    }
}

// K6: h = accz + W_edge @ xsum + b_edge (or 0 for deg==0). Wt2 staged in LDS.
__global__ __launch_bounds__(256) void k_xmm(
        const float2* __restrict__ Wt2, const float* __restrict__ b_edge,
        const float* __restrict__ xsum, const int* __restrict__ rowptr,
        float2* __restrict__ h2, int N) {
    __shared__ float2 swt[ED_D * 64];   // 32 KB
    for (int i = threadIdx.x; i < ED_D * 64; i += 256) swt[i] = Wt2[i];
    __syncthreads();
    int lane = threadIdx.x & 63;
    int wv = threadIdx.x >> 6;
    float2 be2 = ((const float2*)b_edge)[lane];
    for (int n = blockIdx.x * 4 + wv; n < N; n += gridDim.x * 4) {
        int deg = rowptr[n + 1] - rowptr[n];
        if (deg == 0) {
            h2[(size_t)n * 64 + lane] = make_float2(0.f, 0.f);
            continue;
        }
        float xk = xsum[(size_t)n * 64 + lane];
        float2 hv = h2[(size_t)n * 64 + lane];
        hv.x += be2.x; hv.y += be2.y;
#pragma unroll 8
        for (int k = 0; k < 64; ++k) {
            float a = __shfl(xk, k);
            float2 w2 = swt[k * 64 + lane];
            hv.x = fmaf(a, w2.x, hv.x);
            hv.y = fmaf(a, w2.y, hv.y);
        }
        h2[(size_t)n * 64 + lane] = hv;
    }
}

extern "C" void kernel_launch(void* const* d_in, const int* in_sizes, int n_in,
                              void* d_out, int out_size, void* d_ws, size_t ws_size,
                              hipStream_t stream) {
    const float* nfeat = (const float*)d_in[0];
    const float* ex    = (const float*)d_in[1];
    const int*   src   = (const int*)d_in[2];
    const int*   dst   = (const int*)d_in[3];
    const float* W_fc  = (const float*)d_in[4];
    const float* b_fc  = (const float*)d_in[5];
    const float* W_att = (const float*)d_in[6];
    const float* b_att = (const float*)d_in[7];
    const float* W_edge = (const float*)d_in[8];
    const float* b_edge = (const float*)d_in[9];
    const float* W_eatt = (const float*)d_in[10];
    const float* b_eatt = (const float*)d_in[11];
    int N = in_sizes[0] / IN_D;
    int E = in_sizes[2];

    float* h_out = (float*)d_out;
    float* alpha_out = h_out + (size_t)N * OUT_D;

    char* w = (char*)d_ws;
    auto alloc = [&](size_t bytes) { char* p = w; w += (bytes + 255) & ~255ull; return p; };
    unsigned short* zb = (unsigned short*)alloc((size_t)N * OUT_D * 2);
    float* asrc   = (float*)alloc((size_t)N * 4);
    float* adst   = (float*)alloc((size_t)N * 4);
    int* cnt      = (int*)alloc((size_t)N * 4);
    int* rowptr   = (int*)alloc(((size_t)N + 1) * 4);
    int* rank     = (int*)alloc((size_t)E * 4);
    int* eid_csr  = (int*)alloc((size_t)E * 4);
    int* src_csr  = (int*)alloc((size_t)E * 4);
    float* xsum   = (float*)alloc((size_t)N * ED_D * 4);
    unsigned short* Wb = (unsigned short*)alloc((size_t)IN_D * OUT_D * 2);
    float2* Wt2   = (float2*)alloc((size_t)ED_D * 64 * 8);
    float* u      = (float*)alloc(64 * 4);
    float* c0     = (float*)alloc(4);

    int init_total = N > IN_D * OUT_D ? N : IN_D * OUT_D;
    k_init<<<(init_total + 255) / 256, 256, 0, stream>>>(
        W_att, b_att, W_eatt, b_eatt, W_fc, W_edge, u, c0, Wb, Wt2, cnt, N);
    k_hist<<<(E + 255) / 256, 256, 0, stream>>>(dst, cnt, rank, E);
    k_node<<<(N + 63) / 64, 256, 0, stream>>>(nfeat, Wb, b_fc, W_att, zb, asrc, adst, N);
    k_scan<<<1, 1024, 0, stream>>>(cnt, rowptr, N);
    k_fill<<<(E + 255) / 256, 256, 0, stream>>>(dst, src, rank, rowptr, eid_csr, src_csr, E);
    k_fused<<<(N + 3) / 4, 256, 0, stream>>>(zb, ex, eid_csr, src_csr, rowptr, asrc, adst,
                                             u, c0, h_out, alpha_out, xsum, N);
    k_xmm<<<(N + 3) / 4, 256, 0, stream>>>((const float2*)Wt2, b_edge, xsum, rowptr,
                                           (float2*)h_out, N);
}

// Round 21
// 344.698 us; speedup vs baseline: 1.0109x; 1.0109x over previous
//
#include <hip/hip_runtime.h>
#include <math.h>
#include <float.h>

#define IN_D 256
#define OUT_D 128
#define ED_D 64
#define NEG 0.2f

typedef __attribute__((ext_vector_type(8))) short bf16x8;
typedef __attribute__((ext_vector_type(4))) float f32x4;

__device__ __forceinline__ unsigned short f2bf(float f) {
    unsigned u = __float_as_uint(f);
    unsigned r = (u + 0x7FFFu + ((u >> 16) & 1u)) >> 16;   // RNE
    return (unsigned short)r;
}
__device__ __forceinline__ float bf2f(unsigned short h) {
    return __uint_as_float((unsigned)h << 16);
}

// K0: zero cnt; build Wb (bf16 W_fc^T pre-swizzled into MFMA B-fragment layout);
// build Wt2 (W_edge^T as float2 for k_xmm); fold ex_t branch into u, c0.
__global__ __launch_bounds__(256) void k_init(
        const float* __restrict__ W_att, const float* __restrict__ b_att,
        const float* __restrict__ W_eatt, const float* __restrict__ b_eatt,
        const float* __restrict__ W_fc, const float* __restrict__ W_edge,
        float* __restrict__ u, float* __restrict__ c0,
        unsigned short* __restrict__ Wb, float2* __restrict__ Wt2,
        int* __restrict__ cnt, int N) {
    int idx = blockIdx.x * 256 + threadIdx.x;
    if (idx < N) cnt[idx] = 0;
    if (idx < IN_D * OUT_D) {                 // 32768 = 8ks * 8nt * 64lane * 8i
        int i = idx & 7;
        int lane = (idx >> 3) & 63;
        int rest = idx >> 9;
        int nt = rest & 7, ks = rest >> 3;
        int col = nt * 16 + (lane & 15);
        int k = ks * 32 + (lane >> 4) * 8 + i;
        Wb[idx] = f2bf(W_fc[col * IN_D + k]);
    }
    if (idx < ED_D * (OUT_D / 2)) {           // 4096: Wt2[k*64+l] = {We[2l][k], We[2l+1][k]}
        int k = idx >> 6, l = idx & 63;
        Wt2[idx] = make_float2(W_edge[(2 * l) * ED_D + k], W_edge[(2 * l + 1) * ED_D + k]);
    }
    if (idx < ED_D) {
        float acc = 0.f;
        for (int j = 0; j < ED_D; ++j) acc += W_att[256 + j] * W_eatt[j * ED_D + idx];
        u[idx] = acc;
    }
    if (idx == ED_D) {
        float c = 0.f;
        for (int j = 0; j < ED_D; ++j) c += W_att[256 + j] * b_eatt[j];
        c0[0] = c + b_att[0];
    }
}

// K1: dst-degree histogram + per-edge within-bucket rank (atomic return value, free).
__global__ __launch_bounds__(256) void k_hist(const int* __restrict__ dst,
                                              int* __restrict__ cnt,
                                              int* __restrict__ rank, int E) {
    int i = blockIdx.x * 256 + threadIdx.x;
    if (i < E) rank[i] = atomicAdd(&cnt[dst[i]], 1);
}

// K2: bf16-MFMA GEMM  z = nfeat @ W_fc^T + b_fc  [N,128], f32 accumulate (round-12 form).
#define LDA 272
__global__ __launch_bounds__(256) void k_node(
        const float* __restrict__ nfeat, const unsigned short* __restrict__ Wb,
        const float* __restrict__ b_fc, const float* __restrict__ W_att,
        unsigned short* __restrict__ zb, float* __restrict__ asrc,
        float* __restrict__ adst, int n) {
    __shared__ unsigned short sa[128 * LDA];   // 68 KB
    int t = threadIdx.x;
    int row_base = blockIdx.x * 128;

    int r8 = t >> 3, c8 = t & 7;
#pragma unroll
    for (int p = 0; p < 4; ++p) {
        int r = p * 32 + r8;
        int node = row_base + r; if (node >= n) node = n - 1;
        const float4* srcp = (const float4*)(nfeat + (size_t)node * IN_D);
#pragma unroll
        for (int q = 0; q < 8; ++q) {
            int c4 = q * 8 + c8;
            float4 v = srcp[c4];
            unsigned pk0 = (unsigned)f2bf(v.x) | ((unsigned)f2bf(v.y) << 16);
            unsigned pk1 = (unsigned)f2bf(v.z) | ((unsigned)f2bf(v.w) << 16);
            *(uint2*)&sa[(size_t)r * LDA + c4 * 4] = make_uint2(pk0, pk1);
        }
    }
    __syncthreads();

    int lane = t & 63, w = t >> 6;
    int lr = lane & 15, lg = lane >> 4;

    f32x4 acc[2][8];
#pragma unroll
    for (int mi = 0; mi < 2; ++mi)
#pragma unroll
        for (int nt = 0; nt < 8; ++nt) acc[mi][nt] = (f32x4)(0.f);

    const bf16x8* wb8 = (const bf16x8*)Wb;
#pragma unroll
    for (int ks = 0; ks < 8; ++ks) {
        bf16x8 af[2], bfr[8];
#pragma unroll
        for (int mi = 0; mi < 2; ++mi) {
            int row = (2 * w + mi) * 16 + lr;
            af[mi] = *(const bf16x8*)&sa[(size_t)row * LDA + ks * 32 + lg * 8];
        }
#pragma unroll
        for (int nt = 0; nt < 8; ++nt)
            bfr[nt] = wb8[(ks * 8 + nt) * 64 + lane];
#pragma unroll
        for (int mi = 0; mi < 2; ++mi)
#pragma unroll
            for (int nt = 0; nt < 8; ++nt)
                acc[mi][nt] = __builtin_amdgcn_mfma_f32_16x16x32_bf16(
                    af[mi], bfr[nt], acc[mi][nt], 0, 0, 0);
    }

    float w1c[8], w2c[8], bfc[8];
#pragma unroll
    for (int nt = 0; nt < 8; ++nt) {
        int col = nt * 16 + lr;
        w1c[nt] = W_att[col];
        w2c[nt] = W_att[128 + col];
        bfc[nt] = b_fc[col];
    }
#pragma unroll
    for (int mi = 0; mi < 2; ++mi) {
        float p1[4] = {0.f, 0.f, 0.f, 0.f}, p2[4] = {0.f, 0.f, 0.f, 0.f};
#pragma unroll
        for (int nt = 0; nt < 8; ++nt) {
#pragma unroll
            for (int reg = 0; reg < 4; ++reg) {
                float zv = acc[mi][nt][reg] + bfc[nt];
                int m = row_base + (2 * w + mi) * 16 + lg * 4 + reg;
                if (m < n) zb[(size_t)m * OUT_D + nt * 16 + lr] = f2bf(zv);
                p1[reg] = fmaf(zv, w1c[nt], p1[reg]);
                p2[reg] = fmaf(zv, w2c[nt], p2[reg]);
            }
        }
#pragma unroll
        for (int reg = 0; reg < 4; ++reg) {
#pragma unroll
            for (int off = 1; off <= 8; off <<= 1) {
                p1[reg] += __shfl_xor(p1[reg], off);
                p2[reg] += __shfl_xor(p2[reg], off);
            }
        }
        if (lr == 0) {
#pragma unroll
            for (int reg = 0; reg < 4; ++reg) {
                int m = row_base + (2 * w + mi) * 16 + lg * 4 + reg;
                if (m < n) { asrc[m] = p1[reg]; adst[m] = p2[reg]; }
            }
        }
    }
}

// K3: exclusive scan of cnt -> rowptr (single block).
__global__ __launch_bounds__(1024) void k_scan(const int* __restrict__ cnt,
                                               int* __restrict__ rowptr, int N) {
    int t = threadIdx.x;
    int per = (N + 1023) / 1024;
    int b0 = t * per, b1 = b0 + per;
    if (b0 > N) b0 = N;
    if (b1 > N) b1 = N;
    int s = 0;
    for (int i = b0; i < b1; ++i) s += cnt[i];
    int wl = t & 63, w = t >> 6;
    int v = s;
#pragma unroll
    for (int off = 1; off < 64; off <<= 1) {
        int a = __shfl_up(v, off);
        if (wl >= off) v += a;
    }
    __shared__ int wsum[16], woff[16];
    if (wl == 63) wsum[w] = v;
    __syncthreads();
    if (t == 0) { int r = 0; for (int i = 0; i < 16; ++i) { woff[i] = r; r += wsum[i]; } }
    __syncthreads();
    int run = woff[w] + v - s;
    for (int i = b0; i < b1; ++i) { rowptr[i] = run; run += cnt[i]; }
    if (t == 1023) rowptr[N] = run;
}

// K4: build CSR edge/src lists (atomic-free via rank).
__global__ __launch_bounds__(256) void k_fill(
        const int* __restrict__ dst, const int* __restrict__ src,
        const int* __restrict__ rank, const int* __restrict__ rowptr,
        int* __restrict__ eid_csr, int* __restrict__ src_csr, int E) {
    int i = blockIdx.x * 256 + threadIdx.x;
    if (i >= E) return;
    int d = dst[i];
    int pos = rowptr[d] + rank[i];
    eid_csr[pos] = i;
    src_csr[pos] = src[i];
}

// K5 (fused edge-score + softmax + gather): one wave per node, no LDS.
// Pass A: QUAD-chain tier (16 edges/iter, 4 independent load+reduce chains).
// Pass B: 16-edge tier + 8/4/2 remainder tiers. Softmax wave-local.
__global__ __launch_bounds__(256) void k_fused(
        const unsigned short* __restrict__ zb, const float* __restrict__ ex,
        const int* __restrict__ eid_csr, const int* __restrict__ src_csr,
        const int* __restrict__ rowptr,
        const float* __restrict__ asrc, const float* __restrict__ adst,
        const float* __restrict__ u, const float* __restrict__ c0,
        float* __restrict__ h, float* __restrict__ alpha_out,
        float* __restrict__ xsum, int N) {
    int lane = threadIdx.x & 63;
    int half = lane >> 5, hl = lane & 31;
    int n = blockIdx.x * 4 + (threadIdx.x >> 6);
    if (n >= N) return;
    int beg = rowptr[n], end = rowptr[n + 1];
    int deg = end - beg;
    if (deg == 0) return;   // k_xmm writes h=0
    float adn = adst[n], cc = c0[0];
    const float2* ex2 = (const float2*)ex;
    const ushort4* z4 = (const ushort4*)zb;

    if (deg <= 64) {
        int el = 0, sl = 0;
        if (lane < deg) {
            el = eid_csr[beg + lane];
            sl = src_csr[beg + lane];
        }
        // ---- pass A: logits (quarter-wave float4, QUAD independent chains) ----
        int qh = lane >> 4, ql = lane & 15;
        const float4* ex4 = (const float4*)ex;
        float4 u4q = ((const float4*)u)[ql];
        float lg = -FLT_MAX;
        for (int j = 0; j < deg; j += 16) {
            int jq[4], eq[4];
#pragma unroll
            for (int cch = 0; cch < 4; ++cch) {
                jq[cch] = j + 4 * cch + qh;
                eq[cch] = __shfl(el, (jq[cch] < deg) ? jq[cch] : (deg - 1));
            }
            float4 xv[4];
#pragma unroll
            for (int cch = 0; cch < 4; ++cch)
                xv[cch] = ex4[(size_t)eq[cch] * 16 + ql];
            float d[4];
#pragma unroll
            for (int cch = 0; cch < 4; ++cch)
                d[cch] = fmaf(xv[cch].x, u4q.x, fmaf(xv[cch].y, u4q.y,
                          fmaf(xv[cch].z, u4q.z, xv[cch].w * u4q.w)));
#pragma unroll
            for (int off = 8; off >= 1; off >>= 1) {
#pragma unroll
                for (int cch = 0; cch < 4; ++cch)
                    d[cch] += __shfl_xor(d[cch], off);
            }
            int rel = lane - j;
            int src_lane = (rel & 3) * 16;      // quarter q holds edge (base + q)'s dot
            float dl[4];
#pragma unroll
            for (int cch = 0; cch < 4; ++cch)
                dl[cch] = __shfl(d[cch], src_lane);
            if (lane < deg && rel >= 0 && rel < 16)
                lg = dl[rel >> 2];
        }
        if (lane < deg) {
            lg += asrc[sl] + adn + cc;
            lg = (lg > 0.f) ? lg : NEG * lg;
        }
        // ---- softmax ----
        float m = lg;
#pragma unroll
        for (int off = 32; off >= 1; off >>= 1) m = fmaxf(m, __shfl_xor(m, off));
        float wvv = (lane < deg) ? expf(lg - m) : 0.f;
        float sw = wvv;
#pragma unroll
        for (int off = 32; off >= 1; off >>= 1) sw += __shfl_xor(sw, off);
        float al = wvv / sw;          // 0 for invalid lanes
        if (lane < deg) alpha_out[el] = al;
        // ---- pass B: weighted accumulation (rows L2-hot from pass A) ----
        float4 accz = make_float4(0.f, 0.f, 0.f, 0.f);
        float2 accx = make_float2(0.f, 0.f);
        int j = 0;
        for (; j + 16 <= deg; j += 16) {   // 8 pairs = 16 edges, 16 loads in flight
            float a[8]; int s[8], e[8];
#pragma unroll
            for (int q = 0; q < 8; ++q) {
                int idx = j + 2 * q + half;
                a[q] = __shfl(al, idx);
                s[q] = __shfl(sl, idx);
                e[q] = __shfl(el, idx);
            }
            ushort4 zu[8]; float2 xv[8];
#pragma unroll
            for (int q = 0; q < 8; ++q) {
                zu[q] = z4[(size_t)s[q] * 32 + hl];
                xv[q] = ex2[(size_t)e[q] * 32 + hl];
            }
#pragma unroll
            for (int q = 0; q < 8; ++q) {
                accz.x = fmaf(a[q], bf2f(zu[q].x), accz.x);
                accz.y = fmaf(a[q], bf2f(zu[q].y), accz.y);
                accz.z = fmaf(a[q], bf2f(zu[q].z), accz.z);
                accz.w = fmaf(a[q], bf2f(zu[q].w), accz.w);
                accx.x = fmaf(a[q], xv[q].x, accx.x);
                accx.y = fmaf(a[q], xv[q].y, accx.y);
            }
        }
        if (j + 8 <= deg) {              // 4 pairs = 8 edges
            float a[4]; int s[4], e[4];
#pragma unroll
            for (int q = 0; q < 4; ++q) {
                int idx = j + 2 * q + half;
                a[q] = __shfl(al, idx);
                s[q] = __shfl(sl, idx);
                e[q] = __shfl(el, idx);
            }
            ushort4 zu[4]; float2 xv[4];
#pragma unroll
            for (int q = 0; q < 4; ++q) {
                zu[q] = z4[(size_t)s[q] * 32 + hl];
                xv[q] = ex2[(size_t)e[q] * 32 + hl];
            }
#pragma unroll
            for (int q = 0; q < 4; ++q) {
                accz.x = fmaf(a[q], bf2f(zu[q].x), accz.x);
                accz.y = fmaf(a[q], bf2f(zu[q].y), accz.y);
                accz.z = fmaf(a[q], bf2f(zu[q].z), accz.z);
                accz.w = fmaf(a[q], bf2f(zu[q].w), accz.w);
                accx.x = fmaf(a[q], xv[q].x, accx.x);
                accx.y = fmaf(a[q], xv[q].y, accx.y);
            }
            j += 8;
        }
        if (j + 4 <= deg) {              // 2 pairs = 4 edges
            float a[2]; int s[2], e[2];
#pragma unroll
            for (int q = 0; q < 2; ++q) {
                int idx = j + 2 * q + half;
                a[q] = __shfl(al, idx);
                s[q] = __shfl(sl, idx);
                e[q] = __shfl(el, idx);
            }
            ushort4 zu[2]; float2 xv[2];
#pragma unroll
            for (int q = 0; q < 2; ++q) {
                zu[q] = z4[(size_t)s[q] * 32 + hl];
                xv[q] = ex2[(size_t)e[q] * 32 + hl];
            }
#pragma unroll
            for (int q = 0; q < 2; ++q) {
                accz.x = fmaf(a[q], bf2f(zu[q].x), accz.x);
                accz.y = fmaf(a[q], bf2f(zu[q].y), accz.y);
                accz.z = fmaf(a[q], bf2f(zu[q].z), accz.z);
                accz.w = fmaf(a[q], bf2f(zu[q].w), accz.w);
                accx.x = fmaf(a[q], xv[q].x, accx.x);
                accx.y = fmaf(a[q], xv[q].y, accx.y);
            }
            j += 4;
        }
        for (; j < deg; j += 2) {
            int idx = j + half;           // invalid -> al=0, s=e=0 (safe)
            float a = __shfl(al, idx);
            int s = __shfl(sl, idx), e = __shfl(el, idx);
            ushort4 zu = z4[(size_t)s * 32 + hl];
            float2 xv = ex2[(size_t)e * 32 + hl];
            accz.x = fmaf(a, bf2f(zu.x), accz.x);
            accz.y = fmaf(a, bf2f(zu.y), accz.y);
            accz.z = fmaf(a, bf2f(zu.z), accz.z);
            accz.w = fmaf(a, bf2f(zu.w), accz.w);
            accx.x = fmaf(a, xv.x, accx.x);
            accx.y = fmaf(a, xv.y, accx.y);
        }
        accz.x += __shfl_xor(accz.x, 32);
        accz.y += __shfl_xor(accz.y, 32);
        accz.z += __shfl_xor(accz.z, 32);
        accz.w += __shfl_xor(accz.w, 32);
        accx.x += __shfl_xor(accx.x, 32);
        accx.y += __shfl_xor(accx.y, 32);
        if (half == 0) {
            ((float4*)h)[(size_t)n * 32 + hl] = accz;
            ((float2*)xsum)[(size_t)n * 32 + hl] = accx;
        }
    } else {
        // rare slow path (deg>64): online softmax with on-the-fly dot recompute.
        float uv = u[lane];
        float m = -FLT_MAX, ssum = 0.f;
        for (int i = beg; i < end; ++i) {
            int e = eid_csr[i];
            float xv = ex[(size_t)e * ED_D + lane];
            float p = xv * uv;
#pragma unroll
            for (int off = 32; off >= 1; off >>= 1) p += __shfl_xor(p, off);
            float lg = p + asrc[src_csr[i]] + adn + cc;
            lg = (lg > 0.f) ? lg : NEG * lg;
            float mn = fmaxf(m, lg);
            ssum = ssum * expf(m - mn) + expf(lg - mn);
            m = mn;
        }
        float rden = 1.f / ssum;
        const ushort2* z2 = (const ushort2*)zb;
        float2 accz2 = make_float2(0.f, 0.f);
        float accxs = 0.f;
        for (int i = beg; i < end; ++i) {
            int e = eid_csr[i];
            int s = src_csr[i];
            float xv = ex[(size_t)e * ED_D + lane];
            float p = xv * uv;
#pragma unroll
            for (int off = 32; off >= 1; off >>= 1) p += __shfl_xor(p, off);
            float lg = p + asrc[s] + adn + cc;
            lg = (lg > 0.f) ? lg : NEG * lg;
            float al = expf(lg - m) * rden;
            if (lane == 0) alpha_out[e] = al;
            accxs = fmaf(al, xv, accxs);
            ushort2 zz = z2[(size_t)s * ED_D + lane];
            accz2.x = fmaf(al, bf2f(zz.x), accz2.x);
            accz2.y = fmaf(al, bf2f(zz.y), accz2.y);
        }
        ((float2*)h)[(size_t)n * ED_D + lane] = accz2;
        xsum[(size_t)n * ED_D + lane] = accxs;
    }
}

// K6: h = accz + W_edge @ xsum + b_edge (or 0 for deg==0). Wt2 staged in LDS.
__global__ __launch_bounds__(256) void k_xmm(
        const float2* __restrict__ Wt2, const float* __restrict__ b_edge,
        const float* __restrict__ xsum, const int* __restrict__ rowptr,
        float2* __restrict__ h2, int N) {
    __shared__ float2 swt[ED_D * 64];   // 32 KB
    for (int i = threadIdx.x; i < ED_D * 64; i += 256) swt[i] = Wt2[i];
    __syncthreads();
    int lane = threadIdx.x & 63;
    int wv = threadIdx.x >> 6;
    float2 be2 = ((const float2*)b_edge)[lane];
    for (int n = blockIdx.x * 4 + wv; n < N; n += gridDim.x * 4) {
        int deg = rowptr[n + 1] - rowptr[n];
        if (deg == 0) {
            h2[(size_t)n * 64 + lane] = make_float2(0.f, 0.f);
            continue;
        }
        float xk = xsum[(size_t)n * 64 + lane];
        float2 hv = h2[(size_t)n * 64 + lane];
        hv.x += be2.x; hv.y += be2.y;
#pragma unroll 8
        for (int k = 0; k < 64; ++k) {
            float a = __shfl(xk, k);
            float2 w2 = swt[k * 64 + lane];
            hv.x = fmaf(a, w2.x, hv.x);
            hv.y = fmaf(a, w2.y, hv.y);
        }
        h2[(size_t)n * 64 + lane] = hv;
    }
}

extern "C" void kernel_launch(void* const* d_in, const int* in_sizes, int n_in,
                              void* d_out, int out_size, void* d_ws, size_t ws_size,
                              hipStream_t stream) {
    const float* nfeat = (const float*)d_in[0];
    const float* ex    = (const float*)d_in[1];
    const int*   src   = (const int*)d_in[2];
    const int*   dst   = (const int*)d_in[3];
    const float* W_fc  = (const float*)d_in[4];
    const float* b_fc  = (const float*)d_in[5];
    const float* W_att = (const float*)d_in[6];
    const float* b_att = (const float*)d_in[7];
    const float* W_edge = (const float*)d_in[8];
    const float* b_edge = (const float*)d_in[9];
    const float* W_eatt = (const float*)d_in[10];
    const float* b_eatt = (const float*)d_in[11];
    int N = in_sizes[0] / IN_D;
    int E = in_sizes[2];

    float* h_out = (float*)d_out;
    float* alpha_out = h_out + (size_t)N * OUT_D;

    char* w = (char*)d_ws;
    auto alloc = [&](size_t bytes) { char* p = w; w += (bytes + 255) & ~255ull; return p; };
    unsigned short* zb = (unsigned short*)alloc((size_t)N * OUT_D * 2);
    float* asrc   = (float*)alloc((size_t)N * 4);
    float* adst   = (float*)alloc((size_t)N * 4);
    int* cnt      = (int*)alloc((size_t)N * 4);
    int* rowptr   = (int*)alloc(((size_t)N + 1) * 4);
    int* rank     = (int*)alloc((size_t)E * 4);
    int* eid_csr  = (int*)alloc((size_t)E * 4);
    int* src_csr  = (int*)alloc((size_t)E * 4);
    float* xsum   = (float*)alloc((size_t)N * ED_D * 4);
    unsigned short* Wb = (unsigned short*)alloc((size_t)IN_D * OUT_D * 2);
    float2* Wt2   = (float2*)alloc((size_t)ED_D * 64 * 8);
    float* u      = (float*)alloc(64 * 4);
    float* c0     = (float*)alloc(4);

    int init_total = N > IN_D * OUT_D ? N : IN_D * OUT_D;
    k_init<<<(init_total + 255) / 256, 256, 0, stream>>>(
        W_att, b_att, W_eatt, b_eatt, W_fc, W_edge, u, c0, Wb, Wt2, cnt, N);
    k_hist<<<(E + 255) / 256, 256, 0, stream>>>(dst, cnt, rank, E);
    k_node<<<(N + 127) / 128, 256, 0, stream>>>(nfeat, Wb, b_fc, W_att, zb, asrc, adst, N);
    k_scan<<<1, 1024, 0, stream>>>(cnt, rowptr, N);
    k_fill<<<(E + 255) / 256, 256, 0, stream>>>(dst, src, rank, rowptr, eid_csr, src_csr, E);
    k_fused<<<(N + 3) / 4, 256, 0, stream>>>(zb, ex, eid_csr, src_csr, rowptr, asrc, adst,
                                             u, c0, h_out, alpha_out, xsum, N);
    k_xmm<<<(N + 3) / 4, 256, 0, stream>>>((const float2*)Wt2, b_edge, xsum, rowptr,
                                           (float2*)h_out, N);
}